// Round 1
// baseline (181.589 us; speedup 1.0000x reference)
//
#include <hip/hip_runtime.h>

#define N_NODES 50000
#define N_EDGES 800000
#define NBKT 196          // dest buckets of 256 nodes
#define BCAP 6144         // staging capacity per bucket (mean 4096 + 32 sigma)
#define UTS 136           // LDS tile row stride (halves); breaks the stride-128 16-way conflict
#define GBIN 392          // binning blocks in k_binA (2048 edges each)

typedef __attribute__((ext_vector_type(4))) float floatx4;
typedef __attribute__((ext_vector_type(8))) _Float16 half8;
typedef __attribute__((ext_vector_type(4))) _Float16 half4;
typedef __attribute__((ext_vector_type(2))) _Float16 half2v;

// ---- workspace layout (bytes) ----
#define O_PTR   0UL          // int[N] (edge-only CSR starts)
#define O_GF    200192UL     // int[NBKT] (+pad)            -- memset with deg
#define O_DEG   201472UL     // int[N] in-degree (excl self) -- memset with gfill
#define O_DINV  401664UL     // float[N]
#define O_ESRC  601856UL     // int[N_EDGES] 3.2MB
#define O_W1    3801856UL    // f16[128*128] (transposed [n][k])
#define O_W2    3834624UL    // f16[64*128]  (transposed [n][k])
#define O_STG   3851008UL    // u32 staging[NBKT*BCAP] = 4.8MB
#define O_H16   8667904UL    // f16[N*128] dinv-prescaled h
// end: 21467904 bytes (previous proven footprint was 29.45MB, so ws is large enough)

// Pass A: coarse-bin edges by dest>>8 into per-bucket staging runs, and build
// the exact per-node in-degree histogram (global atomics, ~16 avg/counter).
// Blocks [GBIN, GBIN+96) transpose the weights to f16 (independent work that
// rides along to fill the otherwise idle CUs).
// Index width (int32 vs int64) probed per-block from the first 64 odd words.
__global__ __launch_bounds__(256) void k_binA(const int* __restrict__ ei,
                                              int* __restrict__ gfill,
                                              unsigned* __restrict__ staging,
                                              int* __restrict__ deg,
                                              const float* __restrict__ Wg,
                                              const float* __restrict__ Wf,
                                              _Float16* __restrict__ W1,
                                              _Float16* __restrict__ W2) {
    int b = blockIdx.x, t = threadIdx.x;
    if (b >= GBIN) {                               // weight-transpose aux blocks
        int wb = b - GBIN;
        if (wb < 64) {
            int i = wb * 256 + t;                  // W1: 16384 elems
            int n = i >> 7, k = i & 127;
            W1[i] = (_Float16)Wg[k * 128 + n];
        } else {
            int i = (wb - 64) * 256 + t;           // W2: 8192 elems
            int n = i >> 7, k = i & 127;
            W2[i] = (_Float16)Wf[k * 64 + n];
        }
        return;
    }
    __shared__ int cnt[NBKT];
    __shared__ int gbase[NBKT];
    __shared__ int s_i64;
    if (t < 64) {                                  // wave 0: int64 probe
        unsigned w = ((const unsigned*)ei)[2 * t + 1];
        unsigned long long m = __ballot(w == 0u);
        if (t == 0) s_i64 = (__popcll(m) >= 60) ? 1 : 0;
    }
    for (int i = t; i < NBKT; i += 256) cnt[i] = 0;
    __syncthreads();
    bool i64 = s_i64 != 0;
    int e0 = b * 2048 + t * 8;                     // 8 edges per thread
    int sv[8], dvv[8];
    if (i64) {
        const int4* ps = (const int4*)(ei) + (e0 >> 1);
        const int4* pd = (const int4*)(ei + 2 * (size_t)N_EDGES) + (e0 >> 1);
#pragma unroll
        for (int g = 0; g < 4; ++g) {
            if (e0 + 2 * g < N_EDGES) {
                int4 s4 = ps[g], d4 = pd[g];
                sv[2 * g] = s4.x; sv[2 * g + 1] = s4.z;
                dvv[2 * g] = d4.x; dvv[2 * g + 1] = d4.z;
            } else { dvv[2 * g] = -1; dvv[2 * g + 1] = -1; }
        }
    } else {
        const int4* ps = (const int4*)(ei) + (e0 >> 2);
        const int4* pd = (const int4*)(ei + (size_t)N_EDGES) + (e0 >> 2);
#pragma unroll
        for (int g = 0; g < 2; ++g) {
            if (e0 + 4 * g < N_EDGES) {
                int4 s4 = ps[g], d4 = pd[g];
                sv[4 * g] = s4.x; sv[4 * g + 1] = s4.y; sv[4 * g + 2] = s4.z; sv[4 * g + 3] = s4.w;
                dvv[4 * g] = d4.x; dvv[4 * g + 1] = d4.y; dvv[4 * g + 2] = d4.z; dvv[4 * g + 3] = d4.w;
            } else { dvv[4 * g] = -1; dvv[4 * g + 1] = -1; dvv[4 * g + 2] = -1; dvv[4 * g + 3] = -1; }
        }
    }
    unsigned pk[8]; int rk[8]; short bk[8];
#pragma unroll
    for (int j = 0; j < 8; ++j) {
        int d = dvv[j];
        if (d >= 0 && e0 + j < N_EDGES) {
            int bkt = d >> 8;
            bk[j] = (short)bkt;
            pk[j] = (unsigned)sv[j] | ((unsigned)(d & 255) << 16);
            rk[j] = atomicAdd(&cnt[bkt], 1);
            atomicAdd(&deg[d], 1);                 // exact in-degree (fire-and-forget)
        } else bk[j] = -1;
    }
    __syncthreads();
    for (int i = t; i < NBKT; i += 256)
        gbase[i] = atomicAdd(&gfill[i], cnt[i]);
    __syncthreads();
#pragma unroll
    for (int j = 0; j < 8; ++j) {
        if (bk[j] >= 0) {
            int pos = gbase[bk[j]] + rk[j];
            if (pos < BCAP) staging[(size_t)bk[j] * BCAP + pos] = pk[j];
        }
    }
}

// Pass B, blocks [0, NBKT): per-bucket edge-only CSR (ptr/esrc) from staging.
// Blocks [NBKT, NBKT+196): dinv = rsqrt(deg+1) and dinv-prescaled h16 with
// float4->half4 vectorized conversion. The two halves run concurrently.
__global__ __launch_bounds__(256) void k_binB(const unsigned* __restrict__ staging,
                                              const int* __restrict__ gfill,
                                              const int* __restrict__ deg,
                                              const float* __restrict__ h,
                                              int* __restrict__ ptr,
                                              float* __restrict__ dinv,
                                              _Float16* __restrict__ h16,
                                              int* __restrict__ esrc) {
    int b = blockIdx.x, t = threadIdx.x;
    if (b >= NBKT) {                               // dinv + h16 aux blocks
        __shared__ float sdv[256];
        int nb = (b - NBKT) * 256;
        int nn = min(256, N_NODES - nb);
        if (t < nn) {
            float dv = rsqrtf((float)(deg[nb + t] + 1));   // +1 = self-loop
            dinv[nb + t] = dv;
            sdv[t] = dv;
        }
        __syncthreads();
        const floatx4* src = (const floatx4*)(h + (size_t)nb * 128);
        half4* dst = (half4*)(h16 + (size_t)nb * 128);
        int nq = nn * 32;                          // 32 float4 per 128-wide row
        for (int i = t; i < nq; i += 256) {
            floatx4 v = src[i];
            float s = sdv[i >> 5];
            half4 o;
            o[0] = (_Float16)(v[0] * s); o[1] = (_Float16)(v[1] * s);
            o[2] = (_Float16)(v[2] * s); o[3] = (_Float16)(v[3] * s);
            dst[i] = o;
        }
        return;
    }
    __shared__ unsigned se[BCAP];
    __shared__ int lcnt[256];
    __shared__ int lscan[256];
    __shared__ int cur[256];
    __shared__ int s_cb;
    int nbase = b * 256;
    int nn = min(256, N_NODES - nbase);
    int cnt = min(gfill[b], BCAP);
    if (t < 64) {                                  // edge-CSR base: sum_{i<b} edges_i
        int acc = 0;
        for (int i = t; i < b; i += 64) acc += min(gfill[i], BCAP);
#pragma unroll
        for (int off = 32; off > 0; off >>= 1) acc += __shfl_down(acc, off);
        if (t == 0) s_cb = acc;
    }
    lcnt[t] = 0;
    __syncthreads();
    int cb = s_cb;
    const unsigned* st = staging + (size_t)b * BCAP;
    for (int i = t; i < cnt; i += 256) {
        unsigned p = st[i];
        se[i] = p;
        atomicAdd(&lcnt[p >> 16], 1);
    }
    __syncthreads();
    int v = lcnt[t];
    lscan[t] = v;
    __syncthreads();
    for (int off = 1; off < 256; off <<= 1) {
        int x = (t >= off) ? lscan[t - off] : 0;
        __syncthreads(); lscan[t] += x; __syncthreads();
    }
    int segstart = cb + (lscan[t] - v);
    if (t < nn) {
        ptr[nbase + t] = segstart;
        cur[t] = segstart;
    }
    __syncthreads();
    for (int i = t; i < cnt; i += 256) {           // single-pass scatter
        unsigned p = se[i];
        int pos = atomicAdd(&cur[p >> 16], 1);
        esrc[pos] = (int)(p & 0xffffu);
    }
}

// Fused aggregate + double GEMM. Block = 16 consecutive nodes (grid 3125).
// Gather: round-8 proven form — half2/lane loads, 8-deep MLP, VGPR-lean
// (min 8 waves/EU pinned via launch_bounds; round-9's 16B gather halved
// occupancy 57->27% and cost +30us). UNCHANGED this round.
__global__ __launch_bounds__(256, 8) void k_aggF(const _Float16* __restrict__ h16,
                                                 const int* __restrict__ ptr,
                                                 const int* __restrict__ esrc,
                                                 const float* __restrict__ dinv,
                                                 const _Float16* __restrict__ W1,
                                                 const _Float16* __restrict__ W2,
                                                 const float* __restrict__ bg,
                                                 const float* __restrict__ bfc,
                                                 float* __restrict__ out) {
    __shared__ _Float16 ut[16 * UTS];
    __shared__ _Float16 z[16 * UTS];
    int wave = threadIdx.x >> 6;
    int lane = threadIdx.x & 63;
    int nb = blockIdx.x * 16;
    for (int q = 0; q < 4; ++q) {
        int node = nb + wave * 4 + q;
        int p0 = ptr[node];
        int p1 = (node + 1 < N_NODES) ? ptr[node + 1] : N_EDGES;
        half2v us = *(const half2v*)(h16 + (size_t)node * 128 + lane * 2);
        float a0 = (float)us[0], a1 = (float)us[1];           // self-loop
        for (int base = p0; base < p1; base += 64) {
            int cnt = p1 - base; if (cnt > 64) cnt = 64;
            int idx = 0;
            if (lane < cnt) idx = esrc[base + lane];
            int j = 0;
            for (; j + 8 <= cnt; j += 8) {
                int s0 = __shfl(idx, j),     s1 = __shfl(idx, j + 1);
                int s2 = __shfl(idx, j + 2), s3 = __shfl(idx, j + 3);
                int s4 = __shfl(idx, j + 4), s5 = __shfl(idx, j + 5);
                int s6 = __shfl(idx, j + 6), s7 = __shfl(idx, j + 7);
                half2v u0 = *(const half2v*)(h16 + (size_t)s0 * 128 + lane * 2);
                half2v u1 = *(const half2v*)(h16 + (size_t)s1 * 128 + lane * 2);
                half2v u2 = *(const half2v*)(h16 + (size_t)s2 * 128 + lane * 2);
                half2v u3 = *(const half2v*)(h16 + (size_t)s3 * 128 + lane * 2);
                half2v u4 = *(const half2v*)(h16 + (size_t)s4 * 128 + lane * 2);
                half2v u5 = *(const half2v*)(h16 + (size_t)s5 * 128 + lane * 2);
                half2v u6 = *(const half2v*)(h16 + (size_t)s6 * 128 + lane * 2);
                half2v u7 = *(const half2v*)(h16 + (size_t)s7 * 128 + lane * 2);
                a0 += (float)u0[0] + (float)u1[0] + (float)u2[0] + (float)u3[0]
                    + (float)u4[0] + (float)u5[0] + (float)u6[0] + (float)u7[0];
                a1 += (float)u0[1] + (float)u1[1] + (float)u2[1] + (float)u3[1]
                    + (float)u4[1] + (float)u5[1] + (float)u6[1] + (float)u7[1];
            }
            for (; j + 4 <= cnt; j += 4) {
                int s0 = __shfl(idx, j),     s1 = __shfl(idx, j + 1);
                int s2 = __shfl(idx, j + 2), s3 = __shfl(idx, j + 3);
                half2v u0 = *(const half2v*)(h16 + (size_t)s0 * 128 + lane * 2);
                half2v u1 = *(const half2v*)(h16 + (size_t)s1 * 128 + lane * 2);
                half2v u2 = *(const half2v*)(h16 + (size_t)s2 * 128 + lane * 2);
                half2v u3 = *(const half2v*)(h16 + (size_t)s3 * 128 + lane * 2);
                a0 += (float)u0[0] + (float)u1[0] + (float)u2[0] + (float)u3[0];
                a1 += (float)u0[1] + (float)u1[1] + (float)u2[1] + (float)u3[1];
            }
            for (; j < cnt; ++j) {
                int s = __shfl(idx, j);
                half2v uu = *(const half2v*)(h16 + (size_t)s * 128 + lane * 2);
                a0 += (float)uu[0]; a1 += (float)uu[1];
            }
        }
        float sc = dinv[node];
        int r = wave * 4 + q;
        ut[r * UTS + lane * 2]     = (_Float16)(a0 * sc);
        ut[r * UTS + lane * 2 + 1] = (_Float16)(a1 * sc);
    }
    __syncthreads();
    int quad = lane >> 4, l15 = lane & 15;
    half8 a[4];
#pragma unroll
    for (int kk = 0; kk < 4; ++kk)
        a[kk] = *(const half8*)(ut + l15 * UTS + kk * 32 + quad * 8);
#pragma unroll
    for (int tt = 0; tt < 2; ++tt) {               // GEMM1: wave does 2 of 8 n-tiles
        floatx4 acc = {0.f, 0.f, 0.f, 0.f};
        int n = (wave * 2 + tt) * 16 + l15;
#pragma unroll
        for (int kk = 0; kk < 4; ++kk) {
            half8 bb = *(const half8*)(W1 + n * 128 + kk * 32 + quad * 8);
            acc = __builtin_amdgcn_mfma_f32_16x16x32_f16(a[kk], bb, acc, 0, 0, 0);
        }
        float bias = bg[n];
#pragma unroll
        for (int i = 0; i < 4; ++i)
            z[(quad * 4 + i) * UTS + n] = (_Float16)fmaxf(acc[i] + bias, 0.f);
    }
    __syncthreads();
    half8 a2[4];
#pragma unroll
    for (int kk = 0; kk < 4; ++kk)
        a2[kk] = *(const half8*)(z + l15 * UTS + kk * 32 + quad * 8);
    {                                               // GEMM2: wave does 1 of 4 n-tiles
        floatx4 acc = {0.f, 0.f, 0.f, 0.f};
        int n = wave * 16 + l15;
#pragma unroll
        for (int kk = 0; kk < 4; ++kk) {
            half8 bb = *(const half8*)(W2 + n * 128 + kk * 32 + quad * 8);
            acc = __builtin_amdgcn_mfma_f32_16x16x32_f16(a2[kk], bb, acc, 0, 0, 0);
        }
        float bias = bfc[n];
#pragma unroll
        for (int i = 0; i < 4; ++i)
            out[(size_t)(nb + quad * 4 + i) * 64 + n] = acc[i] + bias;
    }
}

extern "C" void kernel_launch(void* const* d_in, const int* in_sizes, int n_in,
                              void* d_out, int out_size, void* d_ws, size_t ws_size,
                              hipStream_t stream) {
    (void)in_sizes; (void)n_in; (void)out_size; (void)ws_size;
    const float* h  = (const float*)d_in[0];
    const int*   ei = (const int*)d_in[1];
    const float* Wg = (const float*)d_in[2];
    const float* bg = (const float*)d_in[3];
    const float* Wf = (const float*)d_in[4];
    const float* bf = (const float*)d_in[5];
    float* out = (float*)d_out;

    char* ws = (char*)d_ws;
    int*      ptr   = (int*)(ws + O_PTR);
    int*      gfill = (int*)(ws + O_GF);
    int*      deg   = (int*)(ws + O_DEG);
    float*    dinv  = (float*)(ws + O_DINV);
    int*      esrc  = (int*)(ws + O_ESRC);
    _Float16* W1    = (_Float16*)(ws + O_W1);
    _Float16* W2    = (_Float16*)(ws + O_W2);
    unsigned* staging = (unsigned*)(ws + O_STG);
    _Float16* h16   = (_Float16*)(ws + O_H16);

    // one memset covers gfill (+pad) and deg, laid out contiguously
    hipMemsetAsync(ws + O_GF, 0, (size_t)(O_DINV - O_GF), stream);
    k_binA<<<GBIN + 96, 256, 0, stream>>>(ei, gfill, staging, deg, Wg, Wf, W1, W2);
    k_binB<<<NBKT + 196, 256, 0, stream>>>(staging, gfill, deg, h, ptr, dinv, h16, esrc);
    k_aggF<<<N_NODES / 16, 256, 0, stream>>>(h16, ptr, esrc, dinv,
                                             W1, W2, bg, bf, out);
}

// Round 2
// 161.733 us; speedup vs baseline: 1.1228x; 1.1228x over previous
//
#include <hip/hip_runtime.h>

#define N_NODES 50000
#define N_EDGES 800000
#define NBKT 196          // dest buckets of 256 nodes
#define BCAP 6144         // staging capacity per bucket (mean 4096 + 32 sigma)
#define UTS 136           // LDS tile row stride (halves); breaks the stride-128 16-way conflict

typedef __attribute__((ext_vector_type(4))) float floatx4;
typedef __attribute__((ext_vector_type(8))) _Float16 half8;
typedef __attribute__((ext_vector_type(4))) _Float16 half4;
typedef __attribute__((ext_vector_type(2))) _Float16 half2v;

// ---- workspace layout (bytes) ----
#define O_PTR   0UL          // int[N] (edge-only CSR starts)
#define O_GF    200192UL     // int[NBKT]
#define O_DINV  401664UL     // float[N]
#define O_ESRC  601856UL     // int[N_EDGES] 3.2MB
#define O_W1    3801856UL    // f16[128*128] (transposed [n][k])
#define O_W2    3834624UL    // f16[64*128]  (transposed [n][k])
#define O_STG   3851008UL    // u32 staging[NBKT*BCAP] = 4.8MB
#define O_H16   8667904UL    // f16[N*128] dinv-prescaled h
// end: 21467904 bytes

// Pass A: coarse-bin edges by dest>>8 into per-bucket staging runs
// (round-0 proven form: 196 blocks, 16 edges/thread).
// Blocks [NBKT, NBKT+96) transpose the weights to f16 (independent riders).
// Index width (int32 vs int64) probed per-block from the first 64 odd words.
__global__ __launch_bounds__(256) void k_binA(const int* __restrict__ ei,
                                              int* __restrict__ gfill,
                                              unsigned* __restrict__ staging,
                                              const float* __restrict__ Wg,
                                              const float* __restrict__ Wf,
                                              _Float16* __restrict__ W1,
                                              _Float16* __restrict__ W2) {
    int b = blockIdx.x, t = threadIdx.x;
    if (b >= NBKT) {                               // weight-transpose rider blocks
        int wb = b - NBKT;
        if (wb < 64) {
            int i = wb * 256 + t;                  // W1: 16384 elems
            int n = i >> 7, k = i & 127;
            W1[i] = (_Float16)Wg[k * 128 + n];
        } else {
            int i = (wb - 64) * 256 + t;           // W2: 8192 elems
            int n = i >> 7, k = i & 127;
            W2[i] = (_Float16)Wf[k * 64 + n];
        }
        return;
    }
    __shared__ int cnt[NBKT];
    __shared__ int gbase[NBKT];
    __shared__ int s_i64;
    if (t < 64) {                                  // wave 0: int64 probe
        unsigned w = ((const unsigned*)ei)[2 * t + 1];
        unsigned long long m = __ballot(w == 0u);
        if (t == 0) s_i64 = (__popcll(m) >= 60) ? 1 : 0;
    }
    for (int i = t; i < NBKT; i += 256) cnt[i] = 0;
    __syncthreads();
    bool i64 = s_i64 != 0;
    int e0 = b * 4096 + t * 16;                    // 16 edges per thread
    int sv[16], dvv[16];
    if (i64) {
        const int4* ps = (const int4*)(ei) + (e0 >> 1);
        const int4* pd = (const int4*)(ei + 2 * (size_t)N_EDGES) + (e0 >> 1);
#pragma unroll
        for (int g = 0; g < 8; ++g) {
            if (e0 + 2 * g < N_EDGES) {
                int4 s4 = ps[g], d4 = pd[g];
                sv[2 * g] = s4.x; sv[2 * g + 1] = s4.z;
                dvv[2 * g] = d4.x; dvv[2 * g + 1] = d4.z;
            } else { dvv[2 * g] = -1; dvv[2 * g + 1] = -1; }
        }
    } else {
        const int4* ps = (const int4*)(ei) + (e0 >> 2);
        const int4* pd = (const int4*)(ei + (size_t)N_EDGES) + (e0 >> 2);
#pragma unroll
        for (int g = 0; g < 4; ++g) {
            if (e0 + 4 * g < N_EDGES) {
                int4 s4 = ps[g], d4 = pd[g];
                sv[4 * g] = s4.x; sv[4 * g + 1] = s4.y; sv[4 * g + 2] = s4.z; sv[4 * g + 3] = s4.w;
                dvv[4 * g] = d4.x; dvv[4 * g + 1] = d4.y; dvv[4 * g + 2] = d4.z; dvv[4 * g + 3] = d4.w;
            } else { dvv[4 * g] = -1; dvv[4 * g + 1] = -1; dvv[4 * g + 2] = -1; dvv[4 * g + 3] = -1; }
        }
    }
    unsigned pk[16]; int rk[16]; short bk[16];
#pragma unroll
    for (int j = 0; j < 16; ++j) {
        int d = dvv[j];
        if (d >= 0 && e0 + j < N_EDGES) {
            int bkt = d >> 8;
            bk[j] = (short)bkt;
            pk[j] = (unsigned)sv[j] | ((unsigned)(d & 255) << 16);
            rk[j] = atomicAdd(&cnt[bkt], 1);
        } else bk[j] = -1;
    }
    __syncthreads();
    for (int i = t; i < NBKT; i += 256)
        gbase[i] = atomicAdd(&gfill[i], cnt[i]);
    __syncthreads();
#pragma unroll
    for (int j = 0; j < 16; ++j) {
        if (bk[j] >= 0) {
            int pos = gbase[bk[j]] + rk[j];
            if (pos < BCAP) staging[(size_t)bk[j] * BCAP + pos] = pk[j];
        }
    }
}

// Pass B: per-bucket edge-only CSR (ptr/esrc) + dinv from the in-bucket
// histogram (round-0 form, minus the h16 conversion and W transpose).
__global__ __launch_bounds__(256) void k_binB(const unsigned* __restrict__ staging,
                                              const int* __restrict__ gfill,
                                              int* __restrict__ ptr,
                                              float* __restrict__ dinv,
                                              int* __restrict__ esrc) {
    __shared__ unsigned se[BCAP];
    __shared__ int lcnt[256];
    __shared__ int lscan[256];
    __shared__ int cur[256];
    __shared__ int s_cb;
    int b = blockIdx.x, t = threadIdx.x;
    int nbase = b * 256;
    int nn = min(256, N_NODES - nbase);
    int cnt = min(gfill[b], BCAP);
    if (t < 64) {                                  // edge-CSR base: sum_{i<b} edges_i
        int acc = 0;
        for (int i = t; i < b; i += 64) acc += min(gfill[i], BCAP);
#pragma unroll
        for (int off = 32; off > 0; off >>= 1) acc += __shfl_down(acc, off);
        if (t == 0) s_cb = acc;
    }
    lcnt[t] = 0;
    __syncthreads();
    int cb = s_cb;
    const unsigned* st = staging + (size_t)b * BCAP;
    for (int i = t; i < cnt; i += 256) {
        unsigned p = st[i];
        se[i] = p;
        atomicAdd(&lcnt[p >> 16], 1);
    }
    __syncthreads();
    int v = lcnt[t];
    lscan[t] = v;
    __syncthreads();
    for (int off = 1; off < 256; off <<= 1) {
        int x = (t >= off) ? lscan[t - off] : 0;
        __syncthreads(); lscan[t] += x; __syncthreads();
    }
    int segstart = cb + (lscan[t] - v);
    if (t < nn) {
        int node = nbase + t;
        ptr[node] = segstart;
        dinv[node] = rsqrtf((float)(v + 1));       // +1 = self-loop
        cur[t] = segstart;
    }
    __syncthreads();
    for (int i = t; i < cnt; i += 256) {           // single-pass scatter
        unsigned p = se[i];
        int pos = atomicAdd(&cur[p >> 16], 1);
        esrc[pos] = (int)(p & 0xffffu);
    }
}

// h16 = f16(h * dinv[row]) with float4->half4 vectorized conversion.
// 391 blocks x 128 rows: ~38 MB of traffic at ~6 waves/CU -> BW-bound.
__global__ __launch_bounds__(256) void k_conv(const float* __restrict__ h,
                                              const float* __restrict__ dinv,
                                              _Float16* __restrict__ h16) {
    __shared__ float sdv[128];
    int b = blockIdx.x, t = threadIdx.x;
    int nb = b * 128;
    int nn = min(128, N_NODES - nb);
    if (nn <= 0) return;
    if (t < nn) sdv[t] = dinv[nb + t];
    __syncthreads();
    const floatx4* src = (const floatx4*)(h + (size_t)nb * 128);
    half4* dst = (half4*)(h16 + (size_t)nb * 128);
    int nq = nn * 32;                              // 32 float4 per 128-wide row
    for (int i = t; i < nq; i += 256) {
        floatx4 v = src[i];
        float s = sdv[i >> 5];
        half4 o;
        o[0] = (_Float16)(v[0] * s); o[1] = (_Float16)(v[1] * s);
        o[2] = (_Float16)(v[2] * s); o[3] = (_Float16)(v[3] * s);
        dst[i] = o;
    }
}

// Fused aggregate + double GEMM. Block = 16 consecutive nodes (grid 3125).
// Gather: round-8 proven form — half2/lane loads, 8-deep MLP, VGPR-lean
// (min 8 waves/EU pinned via launch_bounds). UNCHANGED.
__global__ __launch_bounds__(256, 8) void k_aggF(const _Float16* __restrict__ h16,
                                                 const int* __restrict__ ptr,
                                                 const int* __restrict__ esrc,
                                                 const float* __restrict__ dinv,
                                                 const _Float16* __restrict__ W1,
                                                 const _Float16* __restrict__ W2,
                                                 const float* __restrict__ bg,
                                                 const float* __restrict__ bfc,
                                                 float* __restrict__ out) {
    __shared__ _Float16 ut[16 * UTS];
    __shared__ _Float16 z[16 * UTS];
    int wave = threadIdx.x >> 6;
    int lane = threadIdx.x & 63;
    int nb = blockIdx.x * 16;
    for (int q = 0; q < 4; ++q) {
        int node = nb + wave * 4 + q;
        int p0 = ptr[node];
        int p1 = (node + 1 < N_NODES) ? ptr[node + 1] : N_EDGES;
        half2v us = *(const half2v*)(h16 + (size_t)node * 128 + lane * 2);
        float a0 = (float)us[0], a1 = (float)us[1];           // self-loop
        for (int base = p0; base < p1; base += 64) {
            int cnt = p1 - base; if (cnt > 64) cnt = 64;
            int idx = 0;
            if (lane < cnt) idx = esrc[base + lane];
            int j = 0;
            for (; j + 8 <= cnt; j += 8) {
                int s0 = __shfl(idx, j),     s1 = __shfl(idx, j + 1);
                int s2 = __shfl(idx, j + 2), s3 = __shfl(idx, j + 3);
                int s4 = __shfl(idx, j + 4), s5 = __shfl(idx, j + 5);
                int s6 = __shfl(idx, j + 6), s7 = __shfl(idx, j + 7);
                half2v u0 = *(const half2v*)(h16 + (size_t)s0 * 128 + lane * 2);
                half2v u1 = *(const half2v*)(h16 + (size_t)s1 * 128 + lane * 2);
                half2v u2 = *(const half2v*)(h16 + (size_t)s2 * 128 + lane * 2);
                half2v u3 = *(const half2v*)(h16 + (size_t)s3 * 128 + lane * 2);
                half2v u4 = *(const half2v*)(h16 + (size_t)s4 * 128 + lane * 2);
                half2v u5 = *(const half2v*)(h16 + (size_t)s5 * 128 + lane * 2);
                half2v u6 = *(const half2v*)(h16 + (size_t)s6 * 128 + lane * 2);
                half2v u7 = *(const half2v*)(h16 + (size_t)s7 * 128 + lane * 2);
                a0 += (float)u0[0] + (float)u1[0] + (float)u2[0] + (float)u3[0]
                    + (float)u4[0] + (float)u5[0] + (float)u6[0] + (float)u7[0];
                a1 += (float)u0[1] + (float)u1[1] + (float)u2[1] + (float)u3[1]
                    + (float)u4[1] + (float)u5[1] + (float)u6[1] + (float)u7[1];
            }
            for (; j + 4 <= cnt; j += 4) {
                int s0 = __shfl(idx, j),     s1 = __shfl(idx, j + 1);
                int s2 = __shfl(idx, j + 2), s3 = __shfl(idx, j + 3);
                half2v u0 = *(const half2v*)(h16 + (size_t)s0 * 128 + lane * 2);
                half2v u1 = *(const half2v*)(h16 + (size_t)s1 * 128 + lane * 2);
                half2v u2 = *(const half2v*)(h16 + (size_t)s2 * 128 + lane * 2);
                half2v u3 = *(const half2v*)(h16 + (size_t)s3 * 128 + lane * 2);
                a0 += (float)u0[0] + (float)u1[0] + (float)u2[0] + (float)u3[0];
                a1 += (float)u0[1] + (float)u1[1] + (float)u2[1] + (float)u3[1];
            }
            for (; j < cnt; ++j) {
                int s = __shfl(idx, j);
                half2v uu = *(const half2v*)(h16 + (size_t)s * 128 + lane * 2);
                a0 += (float)uu[0]; a1 += (float)uu[1];
            }
        }
        float sc = dinv[node];
        int r = wave * 4 + q;
        ut[r * UTS + lane * 2]     = (_Float16)(a0 * sc);
        ut[r * UTS + lane * 2 + 1] = (_Float16)(a1 * sc);
    }
    __syncthreads();
    int quad = lane >> 4, l15 = lane & 15;
    half8 a[4];
#pragma unroll
    for (int kk = 0; kk < 4; ++kk)
        a[kk] = *(const half8*)(ut + l15 * UTS + kk * 32 + quad * 8);
#pragma unroll
    for (int tt = 0; tt < 2; ++tt) {               // GEMM1: wave does 2 of 8 n-tiles
        floatx4 acc = {0.f, 0.f, 0.f, 0.f};
        int n = (wave * 2 + tt) * 16 + l15;
#pragma unroll
        for (int kk = 0; kk < 4; ++kk) {
            half8 bb = *(const half8*)(W1 + n * 128 + kk * 32 + quad * 8);
            acc = __builtin_amdgcn_mfma_f32_16x16x32_f16(a[kk], bb, acc, 0, 0, 0);
        }
        float bias = bg[n];
#pragma unroll
        for (int i = 0; i < 4; ++i)
            z[(quad * 4 + i) * UTS + n] = (_Float16)fmaxf(acc[i] + bias, 0.f);
    }
    __syncthreads();
    half8 a2[4];
#pragma unroll
    for (int kk = 0; kk < 4; ++kk)
        a2[kk] = *(const half8*)(z + l15 * UTS + kk * 32 + quad * 8);
    {                                               // GEMM2: wave does 1 of 4 n-tiles
        floatx4 acc = {0.f, 0.f, 0.f, 0.f};
        int n = wave * 16 + l15;
#pragma unroll
        for (int kk = 0; kk < 4; ++kk) {
            half8 bb = *(const half8*)(W2 + n * 128 + kk * 32 + quad * 8);
            acc = __builtin_amdgcn_mfma_f32_16x16x32_f16(a2[kk], bb, acc, 0, 0, 0);
        }
        float bias = bfc[n];
#pragma unroll
        for (int i = 0; i < 4; ++i)
            out[(size_t)(nb + quad * 4 + i) * 64 + n] = acc[i] + bias;
    }
}

extern "C" void kernel_launch(void* const* d_in, const int* in_sizes, int n_in,
                              void* d_out, int out_size, void* d_ws, size_t ws_size,
                              hipStream_t stream) {
    (void)in_sizes; (void)n_in; (void)out_size; (void)ws_size;
    const float* h  = (const float*)d_in[0];
    const int*   ei = (const int*)d_in[1];
    const float* Wg = (const float*)d_in[2];
    const float* bg = (const float*)d_in[3];
    const float* Wf = (const float*)d_in[4];
    const float* bf = (const float*)d_in[5];
    float* out = (float*)d_out;

    char* ws = (char*)d_ws;
    int*      ptr   = (int*)(ws + O_PTR);
    int*      gfill = (int*)(ws + O_GF);
    float*    dinv  = (float*)(ws + O_DINV);
    int*      esrc  = (int*)(ws + O_ESRC);
    _Float16* W1    = (_Float16*)(ws + O_W1);
    _Float16* W2    = (_Float16*)(ws + O_W2);
    unsigned* staging = (unsigned*)(ws + O_STG);
    _Float16* h16   = (_Float16*)(ws + O_H16);

    hipMemsetAsync(gfill, 0, NBKT * sizeof(int), stream);
    k_binA<<<NBKT + 96, 256, 0, stream>>>(ei, gfill, staging, Wg, Wf, W1, W2);
    k_binB<<<NBKT, 256, 0, stream>>>(staging, gfill, ptr, dinv, esrc);
    k_conv<<<(N_NODES + 127) / 128, 256, 0, stream>>>(h, dinv, h16);
    k_aggF<<<N_NODES / 16, 256, 0, stream>>>(h16, ptr, esrc, dinv,
                                             W1, W2, bg, bf, out);
}